// Round 10
// baseline (268.683 us; speedup 1.0000x reference)
//
#include <hip/hip_runtime.h>
#include <math.h>

typedef __attribute__((ext_vector_type(8))) short  short8;   // 8 bf16 (4 VGPRs) - MFMA A/B frag
typedef __attribute__((ext_vector_type(4))) float  floatx4;  // MFMA C/D frag
typedef __attribute__((ext_vector_type(2))) float  float2v;  // packed pair (v_pk_add_f32)
typedef __attribute__((ext_vector_type(4))) unsigned int uintx4; // 16B vector load

#define NLOCI 8
#define VOCAB 512
#define DDIM  256
#define HID   512
#define NSAMP (8192 * 16)

__device__ __forceinline__ float bitsf(unsigned int u) {
    union { unsigned int u; float f; } c; c.u = u; return c.f;
}
__device__ __forceinline__ unsigned short f2bf(float f) {  // RNE (used in prep, cold path)
    union { float f; unsigned int u; } c; c.f = f;
    unsigned int u = c.u;
    return (unsigned short)((u + 0x7FFFu + ((u >> 16) & 1u)) >> 16);
}
__device__ __forceinline__ unsigned short f2bf_fast(float f) {  // round-half-up, 2 ops
    union { float f; unsigned int u; } c; c.f = f;
    return (unsigned short)((c.u + 0x8000u) >> 16);
}
// tanh-form GELU via exp2+rcp; |diff vs erf-GELU| ~3e-4 << threshold.
__device__ __forceinline__ float gelu_fast(float x) {
    float t = x * x;
    float y = x * __builtin_fmaf(0.035677408f, t, 0.79788456f);
    float e = __builtin_amdgcn_exp2f(y * 2.8853901f);
    float r = __builtin_amdgcn_rcpf(e + 1.0f);
    return x - x * r;
}
// async 16B/lane global->LDS DMA (lane i lands at lds_base + i*16)
__device__ __forceinline__ void async_copy16(const void* g, void* l) {
    __builtin_amdgcn_global_load_lds(
        (const __attribute__((address_space(1))) unsigned int*)g,
        (__attribute__((address_space(3))) unsigned int*)l, 16, 0, 0);
}

// sum 8 loci (packed bf16 pairs) -> GELU -> bf16
__device__ __forceinline__ short8 sum_gelu(const uintx4* g) {
    short8 afrag;
#pragma unroll
    for (int j = 0; j < 4; ++j) {
        float2v u0 = (float2v){bitsf(g[0][j] << 16), bitsf(g[0][j] & 0xFFFF0000u)};
        float2v u1 = (float2v){bitsf(g[1][j] << 16), bitsf(g[1][j] & 0xFFFF0000u)};
        float2v u2 = (float2v){bitsf(g[2][j] << 16), bitsf(g[2][j] & 0xFFFF0000u)};
        float2v u3 = (float2v){bitsf(g[3][j] << 16), bitsf(g[3][j] & 0xFFFF0000u)};
        float2v u4 = (float2v){bitsf(g[4][j] << 16), bitsf(g[4][j] & 0xFFFF0000u)};
        float2v u5 = (float2v){bitsf(g[5][j] << 16), bitsf(g[5][j] & 0xFFFF0000u)};
        float2v u6 = (float2v){bitsf(g[6][j] << 16), bitsf(g[6][j] & 0xFFFF0000u)};
        float2v u7 = (float2v){bitsf(g[7][j] << 16), bitsf(g[7][j] & 0xFFFF0000u)};
        float2v sj = ((u0 + u1) + (u2 + u3)) + ((u4 + u5) + (u6 + u7));
        afrag[2 * j]     = (short)f2bf_fast(gelu_fast(sj[0]));
        afrag[2 * j + 1] = (short)f2bf_fast(gelu_fast(sj[1]));
    }
    return afrag;
}

// ---------------------------------------------------------------------------
// Kernel 1 (merged): blocks [0,512): Tp[l] = tables[l] @ W1-slice, bf16,
// b1 folded into locus 0.  blocks [512,544): W2 transpose+cvt -> W2t.
// XOR-swizzled LDS tiles (32 chunks of 16B per row):
//   element (row, k) lives at row*256 + ((k>>3) ^ (row&31))*8 + (k&7)  [shorts]
// ---------------------------------------------------------------------------
__global__ __launch_bounds__(256) void k_prep(
    const float* __restrict__ tables,   // [8][512][256] f32
    const float* __restrict__ W1,       // [2048][512] f32
    const float* __restrict__ b1,       // [512] f32
    const float* __restrict__ W2,       // [512][256] f32
    unsigned short* __restrict__ Tp,    // [8][512][512] bf16
    unsigned short* __restrict__ W2t)   // [256][512] bf16
{
    __shared__ unsigned short a_lds[64 * 256];   // 32 KB, swizzled
    __shared__ unsigned short bt_lds[64 * 256];  // 32 KB, swizzled (bt[n][k])

    const int t = threadIdx.x;

    if (blockIdx.x >= 512) {
        // ---- W2 transpose+cvt: out[c][r] = bf16(in[r][c]), in [512][256] f32
        const int bid = blockIdx.x - 512;
        const int r0 = (bid & 7) * 64;   // over HID=512 rows
        const int c0 = (bid >> 3) * 64;  // over DDIM=256 cols
        float* tile = (float*)a_lds;     // 64*65*4 = 16.6 KB <= 32 KB
#pragma unroll
        for (int i = 0; i < 16; ++i) {
            int flat = i * 256 + t;
            int rr = flat >> 6, cc = flat & 63;
            tile[rr * 65 + cc] = W2[(r0 + rr) * DDIM + c0 + cc];
        }
        __syncthreads();
#pragma unroll
        for (int i = 0; i < 8; ++i) {
            int flat = i * 256 + t;
            int cc = flat >> 5, rp = (flat & 31) * 2;
            ushort2 v;
            v.x = f2bf(tile[rp * 65 + cc]);
            v.y = f2bf(tile[(rp + 1) * 65 + cc]);
            *(ushort2*)(W2t + (c0 + cc) * HID + r0 + rp) = v;
        }
        return;
    }

    const int l  = blockIdx.x >> 6;
    const int v0 = ((blockIdx.x >> 3) & 7) * 64;
    const int n0 = (blockIdx.x & 7) * 64;

    // ---- stage A (tables tile): float4 coalesced loads, conflict-free writes
    {
        const float* asrc = tables + (l * 512 + v0) * 256;
#pragma unroll
        for (int i = 0; i < 16; ++i) {
            int flat = i * 1024 + t * 4;
            int row = flat >> 8, k = flat & 255;
            float4 v = *(const float4*)(asrc + flat);
            ushort4 pk4;
            pk4.x = f2bf(v.x); pk4.y = f2bf(v.y); pk4.z = f2bf(v.z); pk4.w = f2bf(v.w);
            int chunkX = (k >> 3) ^ (row & 31);
            *(ushort4*)(a_lds + row * 256 + chunkX * 8 + (k & 7)) = pk4;
        }
    }
    // ---- stage B^T: bt[n][k] = bf16(W1[l*256+k][n0+n])
    {
        const int n = t & 63;
        const int kq = (t >> 6) * 64;
        const float* bsrc = W1 + (l * 256) * 512 + n0 + n;
#pragma unroll
        for (int i = 0; i < 8; ++i) {
            int k0 = kq + i * 8;
            short8 pk8;
#pragma unroll
            for (int j = 0; j < 8; ++j)
                pk8[j] = (short)f2bf(bsrc[(k0 + j) * 512]);
            int chunkX = (k0 >> 3) ^ (n & 31);
            *(short8*)(bt_lds + n * 256 + chunkX * 8) = pk8;
        }
    }
    __syncthreads();

    const int wave = t >> 6, lane = t & 63;
    const int p = lane & 15, q = lane >> 4;
    const int arow = wave * 16 + p;

    floatx4 acc[4];
#pragma unroll
    for (int nt = 0; nt < 4; ++nt) acc[nt] = (floatx4){0.f, 0.f, 0.f, 0.f};

#pragma unroll
    for (int kc = 0; kc < 8; ++kc) {
        int cq = kc * 4 + q;
        short8 afrag = *(const short8*)(a_lds + arow * 256 + (cq ^ (arow & 31)) * 8);
#pragma unroll
        for (int nt = 0; nt < 4; ++nt) {
            int brow = nt * 16 + p;
            short8 bfrag = *(const short8*)(bt_lds + brow * 256 + (cq ^ (brow & 31)) * 8);
            acc[nt] = __builtin_amdgcn_mfma_f32_16x16x32_bf16(afrag, bfrag, acc[nt], 0, 0, 0);
        }
    }

    // D: row(M=vocab) = q*4 + r, col(N) = nt*16 + p; fold b1 at l==0
#pragma unroll
    for (int nt = 0; nt < 4; ++nt) {
        int col = n0 + nt * 16 + p;
        float badd = (l == 0) ? b1[col] : 0.0f;
#pragma unroll
        for (int r = 0; r < 4; ++r) {
            int row = v0 + wave * 16 + q * 4 + r;
            Tp[(l * 512 + row) * 512 + col] = f2bf(acc[nt][r] + badd);
        }
    }
}

// ---------------------------------------------------------------------------
// Kernel 2a: k_gather — wave = one sample, lane = one 16B k-chunk.
// ROUND 10 CHANGES:
//  (a) NONTEMPORAL H store. H's 134 MB write stream was allocating in each
//      XCD's 4 MB L2 and sweeping out the 4 MB Tp table, pushing the 1.07 GB
//      of Tp reads from L2-BW (34.5 TB/s) down to L3-BW. The nt hint keeps
//      the write stream out of L2 -> Tp stays resident. (k_gemm reads H from
//      L3 either way: 134 MB >> L2.)
//  (b) readfirstlane(wid): the hap row is wave-uniform -> scalar s_load
//      instead of 8 broadcast VMEM loads per wave.
// The 8 Tp row reads are perfectly coalesced (64 lanes x 16B = the 1KB row);
// ~8 waves/SIMD occupancy, 8 independent loads/wave -> issue-saturated.
// ---------------------------------------------------------------------------
__global__ __launch_bounds__(256) void k_gather(
    const int* __restrict__ hap,              // [131072][8] int32
    const unsigned short* __restrict__ Tp,    // [8][512][512] bf16 (b1 folded)
    unsigned short* __restrict__ H)           // [131072][512] bf16 (= out buffer)
{
    const int wid  = __builtin_amdgcn_readfirstlane(
                         (int)((blockIdx.x * 256 + threadIdx.x) >> 6));  // sample
    const int lane = threadIdx.x & 63;
    const char* Tpc = (const char*)Tp;
    const int* hp = hap + wid * 8;

    uintx4 g[8];
#pragma unroll
    for (int l = 0; l < 8; ++l) {
        unsigned tok = ((unsigned)hp[l]) & 511u;
        g[l] = *(const uintx4*)(Tpc + (unsigned)l * 524288u + tok * 1024u
                                + (unsigned)(lane * 16));
    }
    short8 hv = sum_gelu(g);
    __builtin_nontemporal_store(hv, (short8*)(H + wid * 512 + lane * 8));
}

// ---------------------------------------------------------------------------
// Kernel 2b: k_gemm — out = H @ W2t^T + b2 (M=131072, N=256, K=512).
// 2-phase double-buffered pipeline with counted vmcnt (r9; perf-equal to r8,
// structurally cleaner). LDS 80 KB -> 2 blocks/CU; __launch_bounds__(256,2)
// = 256-VGPR budget -> spill structurally excluded. Zero-conflict XOR layout.
// Alias note: H and out are the SAME buffer; block b reads only rows
// [64b,64b+64) (all DMA reads precede epilogue stores; blocks disjoint).
// ---------------------------------------------------------------------------
__global__ __launch_bounds__(256, 2) void k_gemm(
    const unsigned short* H,                  // [131072][512] bf16 (aliases out)
    const unsigned short* __restrict__ W2t,   // [256][512] bf16
    const float* __restrict__ b2,             // [256] f32
    float* out)                               // [131072][256] f32
{
    __shared__ unsigned short b_lds[2][256 * 64];  // 64 KB, swizzled dbuf
    __shared__ unsigned short a_lds[2][64 * 64];   // 16 KB, swizzled dbuf

    const int t = threadIdx.x;
    const int wave = t >> 6, lane = t & 63;
    const int p = lane & 15, q = lane >> 4;
    const int m_blk = blockIdx.x * 64;

    // DMA lane mapping (both A and B): dest row r = base + (lane>>3),
    // dest slot j = lane&7; source chunk = j ^ (r&7) = jx (r&7 == drow&7).
    const int drow = lane >> 3;
    const int jx   = (lane & 7) ^ (drow & 7);
    const unsigned short* bsrc = W2t + (wave * 64 + drow) * 512 + jx * 8;
    const unsigned short* asrc = H + (m_blk + wave * 16 + drow) * 512 + jx * 8;
    const int p7 = p & 7;

    floatx4 acc[16];
#pragma unroll
    for (int nt = 0; nt < 16; ++nt) acc[nt] = (floatx4){0.f, 0.f, 0.f, 0.f};

    auto stage = [&](int buf, int kb) {
#pragma unroll
        for (int i = 0; i < 8; ++i)
            async_copy16(bsrc + kb * 64 + i * 8 * 512,
                         &b_lds[buf][(wave * 64 + i * 8) * 64]);
#pragma unroll
        for (int i = 0; i < 2; ++i)
            async_copy16(asrc + kb * 64 + i * 8 * 512,
                         &a_lds[buf][(wave * 16 + i * 8) * 64]);
    };

    // prologue: stage tile 0 into buf 0
    stage(0, 0);
    __builtin_amdgcn_sched_barrier(0);

#pragma unroll
    for (int kb = 0; kb < 8; ++kb) {
        const int cur = kb & 1;
        // issue NEXT tile's 10 DMAs before computing current
        if (kb < 7) {
            stage(cur ^ 1, kb + 1);
            __builtin_amdgcn_sched_barrier(0);
        }
        // counted wait: current tile's 10 (oldest) landed; next tile's 10
        // stay in flight across the barrier
        if (kb < 7) { asm volatile("s_waitcnt vmcnt(10)" ::: "memory"); }
        else        { asm volatile("s_waitcnt vmcnt(0)"  ::: "memory"); }
        __builtin_amdgcn_s_barrier();
        __builtin_amdgcn_sched_barrier(0);

#pragma unroll
        for (int s = 0; s < 2; ++s) {
            const int slot = (s * 4 + q) ^ p7;
            short8 afrag = *(const short8*)(&a_lds[cur][(wave * 16 + p) * 64 + slot * 8]);
            const unsigned short* bb = &b_lds[cur][p * 64 + slot * 8];
            __builtin_amdgcn_s_setprio(1);
#pragma unroll
            for (int nt = 0; nt < 16; ++nt) {
                short8 bfrag = *(const short8*)(bb + nt * 1024);
                acc[nt] = __builtin_amdgcn_mfma_f32_16x16x32_bf16(afrag, bfrag, acc[nt], 0, 0, 0);
            }
            __builtin_amdgcn_s_setprio(0);
        }

        // all waves done reading buf cur before it is re-staged at kb+2
        asm volatile("s_waitcnt lgkmcnt(0)" ::: "memory");
        __builtin_amdgcn_s_barrier();
        __builtin_amdgcn_sched_barrier(0);
    }

    // epilogue: D row(M=sample) = q*4+r, col(N) = nt*16+p; add b2, NT store f32
#pragma unroll
    for (int nt = 0; nt < 16; ++nt) {
        int n = nt * 16 + p;
        float b2v = b2[n];
#pragma unroll
        for (int r = 0; r < 4; ++r) {
            int m = m_blk + wave * 16 + q * 4 + r;
            __builtin_nontemporal_store(acc[nt][r] + b2v, out + m * 256 + n);
        }
    }
}

// ---------------------------------------------------------------------------
extern "C" void kernel_launch(void* const* d_in, const int* in_sizes, int n_in,
                              void* d_out, int out_size, void* d_ws, size_t ws_size,
                              hipStream_t stream) {
    const int*   hap    = (const int*)d_in[0];
    const float* tables = (const float*)d_in[1];
    const float* W1     = (const float*)d_in[2];
    const float* b1     = (const float*)d_in[3];
    const float* W2     = (const float*)d_in[4];
    const float* b2     = (const float*)d_in[5];
    float*       outp   = (float*)d_out;

    unsigned short* Tp  = (unsigned short*)d_ws;                        // 4 MB bf16
    unsigned short* W2t = (unsigned short*)d_ws + NLOCI * VOCAB * HID;  // 256 KB
    unsigned short* Hbf = (unsigned short*)d_out;                       // H aliases out

    k_prep<<<dim3(544), dim3(256), 0, stream>>>(tables, W1, b1, W2, Tp, W2t);
    k_gather<<<dim3(NSAMP * 64 / 256), dim3(256), 0, stream>>>(hap, Tp, Hbf);
    k_gemm<<<dim3(NSAMP / 64), dim3(256), 0, stream>>>(Hbf, W2t, b2, outp);
}

// Round 11
// 251.435 us; speedup vs baseline: 1.0686x; 1.0686x over previous
//
#include <hip/hip_runtime.h>
#include <math.h>

typedef __attribute__((ext_vector_type(8))) short  short8;   // 8 bf16 (4 VGPRs) - MFMA A/B frag
typedef __attribute__((ext_vector_type(4))) float  floatx4;  // MFMA C/D frag
typedef __attribute__((ext_vector_type(2))) float  float2v;  // packed pair (v_pk_add_f32)
typedef __attribute__((ext_vector_type(4))) unsigned int uintx4; // 16B vector load

#define NLOCI 8
#define VOCAB 512
#define DDIM  256
#define HID   512
#define NSAMP (8192 * 16)

__device__ __forceinline__ float bitsf(unsigned int u) {
    union { unsigned int u; float f; } c; c.u = u; return c.f;
}
__device__ __forceinline__ unsigned short f2bf(float f) {  // RNE (used in prep, cold path)
    union { float f; unsigned int u; } c; c.f = f;
    unsigned int u = c.u;
    return (unsigned short)((u + 0x7FFFu + ((u >> 16) & 1u)) >> 16);
}
__device__ __forceinline__ unsigned short f2bf_fast(float f) {  // round-half-up, 2 ops
    union { float f; unsigned int u; } c; c.f = f;
    return (unsigned short)((c.u + 0x8000u) >> 16);
}
// tanh-form GELU via exp2+rcp; |diff vs erf-GELU| ~3e-4 << threshold.
__device__ __forceinline__ float gelu_fast(float x) {
    float t = x * x;
    float y = x * __builtin_fmaf(0.035677408f, t, 0.79788456f);
    float e = __builtin_amdgcn_exp2f(y * 2.8853901f);
    float r = __builtin_amdgcn_rcpf(e + 1.0f);
    return x - x * r;
}
// async 16B/lane global->LDS DMA (lane i lands at lds_base + i*16)
__device__ __forceinline__ void async_copy16(const void* g, void* l) {
    __builtin_amdgcn_global_load_lds(
        (const __attribute__((address_space(1))) unsigned int*)g,
        (__attribute__((address_space(3))) unsigned int*)l, 16, 0, 0);
}

// sum 8 loci (packed bf16 pairs) -> GELU -> bf16
__device__ __forceinline__ short8 sum_gelu(const uintx4* g) {
    short8 afrag;
#pragma unroll
    for (int j = 0; j < 4; ++j) {
        float2v u0 = (float2v){bitsf(g[0][j] << 16), bitsf(g[0][j] & 0xFFFF0000u)};
        float2v u1 = (float2v){bitsf(g[1][j] << 16), bitsf(g[1][j] & 0xFFFF0000u)};
        float2v u2 = (float2v){bitsf(g[2][j] << 16), bitsf(g[2][j] & 0xFFFF0000u)};
        float2v u3 = (float2v){bitsf(g[3][j] << 16), bitsf(g[3][j] & 0xFFFF0000u)};
        float2v u4 = (float2v){bitsf(g[4][j] << 16), bitsf(g[4][j] & 0xFFFF0000u)};
        float2v u5 = (float2v){bitsf(g[5][j] << 16), bitsf(g[5][j] & 0xFFFF0000u)};
        float2v u6 = (float2v){bitsf(g[6][j] << 16), bitsf(g[6][j] & 0xFFFF0000u)};
        float2v u7 = (float2v){bitsf(g[7][j] << 16), bitsf(g[7][j] & 0xFFFF0000u)};
        float2v sj = ((u0 + u1) + (u2 + u3)) + ((u4 + u5) + (u6 + u7));
        afrag[2 * j]     = (short)f2bf_fast(gelu_fast(sj[0]));
        afrag[2 * j + 1] = (short)f2bf_fast(gelu_fast(sj[1]));
    }
    return afrag;
}

// ---------------------------------------------------------------------------
// Kernel 1 (merged): blocks [0,512): Tp[l] = tables[l] @ W1-slice, bf16,
// b1 folded into locus 0.  blocks [512,544): W2 transpose+cvt -> W2t.
// XOR-swizzled LDS tiles (32 chunks of 16B per row):
//   element (row, k) lives at row*256 + ((k>>3) ^ (row&31))*8 + (k&7)  [shorts]
// ---------------------------------------------------------------------------
__global__ __launch_bounds__(256) void k_prep(
    const float* __restrict__ tables,   // [8][512][256] f32
    const float* __restrict__ W1,       // [2048][512] f32
    const float* __restrict__ b1,       // [512] f32
    const float* __restrict__ W2,       // [512][256] f32
    unsigned short* __restrict__ Tp,    // [8][512][512] bf16
    unsigned short* __restrict__ W2t)   // [256][512] bf16
{
    __shared__ unsigned short a_lds[64 * 256];   // 32 KB, swizzled
    __shared__ unsigned short bt_lds[64 * 256];  // 32 KB, swizzled (bt[n][k])

    const int t = threadIdx.x;

    if (blockIdx.x >= 512) {
        // ---- W2 transpose+cvt: out[c][r] = bf16(in[r][c]), in [512][256] f32
        const int bid = blockIdx.x - 512;
        const int r0 = (bid & 7) * 64;   // over HID=512 rows
        const int c0 = (bid >> 3) * 64;  // over DDIM=256 cols
        float* tile = (float*)a_lds;     // 64*65*4 = 16.6 KB <= 32 KB
#pragma unroll
        for (int i = 0; i < 16; ++i) {
            int flat = i * 256 + t;
            int rr = flat >> 6, cc = flat & 63;
            tile[rr * 65 + cc] = W2[(r0 + rr) * DDIM + c0 + cc];
        }
        __syncthreads();
#pragma unroll
        for (int i = 0; i < 8; ++i) {
            int flat = i * 256 + t;
            int cc = flat >> 5, rp = (flat & 31) * 2;
            ushort2 v;
            v.x = f2bf(tile[rp * 65 + cc]);
            v.y = f2bf(tile[(rp + 1) * 65 + cc]);
            *(ushort2*)(W2t + (c0 + cc) * HID + r0 + rp) = v;
        }
        return;
    }

    const int l  = blockIdx.x >> 6;
    const int v0 = ((blockIdx.x >> 3) & 7) * 64;
    const int n0 = (blockIdx.x & 7) * 64;

    // ---- stage A (tables tile): float4 coalesced loads, conflict-free writes
    {
        const float* asrc = tables + (l * 512 + v0) * 256;
#pragma unroll
        for (int i = 0; i < 16; ++i) {
            int flat = i * 1024 + t * 4;
            int row = flat >> 8, k = flat & 255;
            float4 v = *(const float4*)(asrc + flat);
            ushort4 pk4;
            pk4.x = f2bf(v.x); pk4.y = f2bf(v.y); pk4.z = f2bf(v.z); pk4.w = f2bf(v.w);
            int chunkX = (k >> 3) ^ (row & 31);
            *(ushort4*)(a_lds + row * 256 + chunkX * 8 + (k & 7)) = pk4;
        }
    }
    // ---- stage B^T: bt[n][k] = bf16(W1[l*256+k][n0+n])
    {
        const int n = t & 63;
        const int kq = (t >> 6) * 64;
        const float* bsrc = W1 + (l * 256) * 512 + n0 + n;
#pragma unroll
        for (int i = 0; i < 8; ++i) {
            int k0 = kq + i * 8;
            short8 pk8;
#pragma unroll
            for (int j = 0; j < 8; ++j)
                pk8[j] = (short)f2bf(bsrc[(k0 + j) * 512]);
            int chunkX = (k0 >> 3) ^ (n & 31);
            *(short8*)(bt_lds + n * 256 + chunkX * 8) = pk8;
        }
    }
    __syncthreads();

    const int wave = t >> 6, lane = t & 63;
    const int p = lane & 15, q = lane >> 4;
    const int arow = wave * 16 + p;

    floatx4 acc[4];
#pragma unroll
    for (int nt = 0; nt < 4; ++nt) acc[nt] = (floatx4){0.f, 0.f, 0.f, 0.f};

#pragma unroll
    for (int kc = 0; kc < 8; ++kc) {
        int cq = kc * 4 + q;
        short8 afrag = *(const short8*)(a_lds + arow * 256 + (cq ^ (arow & 31)) * 8);
#pragma unroll
        for (int nt = 0; nt < 4; ++nt) {
            int brow = nt * 16 + p;
            short8 bfrag = *(const short8*)(bt_lds + brow * 256 + (cq ^ (brow & 31)) * 8);
            acc[nt] = __builtin_amdgcn_mfma_f32_16x16x32_bf16(afrag, bfrag, acc[nt], 0, 0, 0);
        }
    }

    // D: row(M=vocab) = q*4 + r, col(N) = nt*16 + p; fold b1 at l==0
#pragma unroll
    for (int nt = 0; nt < 4; ++nt) {
        int col = n0 + nt * 16 + p;
        float badd = (l == 0) ? b1[col] : 0.0f;
#pragma unroll
        for (int r = 0; r < 4; ++r) {
            int row = v0 + wave * 16 + q * 4 + r;
            Tp[(l * 512 + row) * 512 + col] = f2bf(acc[nt][r] + badd);
        }
    }
}

// ---------------------------------------------------------------------------
// Kernel 2a: k_gather — wave = one sample, lane = one 16B k-chunk.
// (r10's nontemporal H store REVERTED: it pushed H out of L2/L3 and made
//  k_gemm's H reads HBM-sourced — measured +6 µs e2e. Plain stores keep H
//  L3-warm for k_gemm.)  readfirstlane(wid) kept: hap row is wave-uniform.
// The 8 Tp row reads are perfectly coalesced (64 lanes x 16B = the 1KB row).
// H stored inside the output buffer (H row m = out row m's bytes).
// ---------------------------------------------------------------------------
__global__ __launch_bounds__(256) void k_gather(
    const int* __restrict__ hap,              // [131072][8] int32
    const unsigned short* __restrict__ Tp,    // [8][512][512] bf16 (b1 folded)
    unsigned short* __restrict__ H)           // [131072][512] bf16 (= out buffer)
{
    const int wid  = __builtin_amdgcn_readfirstlane(
                         (int)((blockIdx.x * 256 + threadIdx.x) >> 6));  // sample
    const int lane = threadIdx.x & 63;
    const char* Tpc = (const char*)Tp;
    const int* hp = hap + wid * 8;

    uintx4 g[8];
#pragma unroll
    for (int l = 0; l < 8; ++l) {
        unsigned tok = ((unsigned)hp[l]) & 511u;
        g[l] = *(const uintx4*)(Tpc + (unsigned)l * 524288u + tok * 1024u
                                + (unsigned)(lane * 16));
    }
    short8 hv = sum_gelu(g);
    *(short8*)(H + wid * 512 + lane * 8) = hv;
}

// ---------------------------------------------------------------------------
// Kernel 2b: k_gemm — out = H @ W2t^T + b2 (M=131072, N=256, K=512).
// ROUND 11: REGISTER A-FRAGS + SINGLE-BUFFER B -> 4 blocks/CU.
//   r10 counters: 84.6 µs at 18.8% occupancy, no pipe >31% -> latency-bound
//   at 2 blocks/CU. The A-frag for lane (p,q) is a CONTIGUOUS 16B of H
//   (row m_blk+wave*16+p, byte kb*128 + s*64 + q*16) -> load it directly to
//   registers with compile-time imm offsets (<=960B); a_lds deleted, B
//   single-buffered (32 KB) -> LDS 32 KB, 4 blocks/CU. A-regs double-buffer
//   by loop PARITY (full unroll -> static names; no moves of in-flight regs):
//   tile kb+1's 2 A-loads issue after tile kb's B-DMA and stay in flight
//   across the barrier (vmcnt(2)) -> full-tile prefetch distance. Arch live
//   ~50 regs + 64 AGPR acc: genuinely fits the (256,4) budget (the r4/r7
//   spills came from 64-reg gather buffers that no longer exist).
//   Per tile kb:  lgkm0+bar / B-DMA x8 / A(kb+1) x2 / vmcnt(2) / bar /
//                 MFMA s0,s1 x32
// Alias note: H and out are the SAME buffer; block b reads only rows
// [64b,64b+64) (all A reads complete before the epilogue stores; blocks
// disjoint).
// ---------------------------------------------------------------------------
__global__ __launch_bounds__(256, 4) void k_gemm(
    const unsigned short* H,                  // [131072][512] bf16 (aliases out)
    const unsigned short* __restrict__ W2t,   // [256][512] bf16
    const float* __restrict__ b2,             // [256] f32
    float* out)                               // [131072][256] f32
{
    __shared__ unsigned short b_lds[256 * 64];  // 32 KB single buffer, swizzled

    const int t = threadIdx.x;
    const int wave = t >> 6, lane = t & 63;
    const int p = lane & 15, q = lane >> 4;
    const int m_blk = blockIdx.x * 64;

    // B DMA lane mapping: dest row r = wave*64 + (lane>>3), slot j = lane&7;
    // source chunk = j ^ (r&7).
    const int drow = lane >> 3;
    const int jx   = (lane & 7) ^ (drow & 7);
    const unsigned short* bsrc = W2t + (wave * 64 + drow) * 512 + jx * 8;
    const int p7 = p & 7;

    // per-lane A base: row m_blk + wave*16 + p, byte q*16 folded in.
    // A-frag(kb, s) = 16B at abase + kb*128 + s*64   (imm <= 960)
    const char* abase = (const char*)H + (m_blk + wave * 16 + p) * 1024 + q * 16;

    floatx4 acc[16];
#pragma unroll
    for (int nt = 0; nt < 16; ++nt) acc[nt] = (floatx4){0.f, 0.f, 0.f, 0.f};

    // parity-named A-frag double buffer (E = even tiles, O = odd tiles)
    short8 aE0, aE1, aO0, aO1;

    // prologue: A(0)
    aE0 = *(const short8*)(abase + 0);
    aE1 = *(const short8*)(abase + 64);
    __builtin_amdgcn_sched_barrier(0);

#pragma unroll
    for (int kb = 0; kb < 8; ++kb) {
        // barrier 1: all waves done reading b_lds (tile kb-1)
        asm volatile("s_waitcnt lgkmcnt(0)" ::: "memory");
        __builtin_amdgcn_s_barrier();
        __builtin_amdgcn_sched_barrier(0);

        // B(kb): 8 DMA per wave
#pragma unroll
        for (int i = 0; i < 8; ++i)
            async_copy16(bsrc + kb * 64 + i * 8 * 512,
                         b_lds + (wave * 64 + i * 8) * 64);
        __builtin_amdgcn_sched_barrier(0);

        // A(kb+1): 2 reg loads into the OTHER parity (stay in flight across
        // the barrier and the whole MFMA phase)
        if (kb < 7) {
            if ((kb & 1) == 0) {
                aO0 = *(const short8*)(abase + (kb + 1) * 128);
                aO1 = *(const short8*)(abase + (kb + 1) * 128 + 64);
            } else {
                aE0 = *(const short8*)(abase + (kb + 1) * 128);
                aE1 = *(const short8*)(abase + (kb + 1) * 128 + 64);
            }
            __builtin_amdgcn_sched_barrier(0);
        }

        // counted wait: A(kb) [oldest 2] + B(kb) [8] landed; A(kb+1) flying
        if (kb < 7) { asm volatile("s_waitcnt vmcnt(2)" ::: "memory"); }
        else        { asm volatile("s_waitcnt vmcnt(0)" ::: "memory"); }
        __builtin_amdgcn_s_barrier();
        __builtin_amdgcn_sched_barrier(0);

        // MFMA: 2 slices x 16 n-tiles from the zero-conflict XOR layout
#pragma unroll
        for (int s = 0; s < 2; ++s) {
            const short8 afrag = ((kb & 1) == 0) ? (s == 0 ? aE0 : aE1)
                                                 : (s == 0 ? aO0 : aO1);
            const unsigned short* bb = b_lds + p * 64 + (((s * 4 + q) ^ p7) * 8);
            __builtin_amdgcn_s_setprio(1);
#pragma unroll
            for (int nt = 0; nt < 16; ++nt) {
                short8 bfrag = *(const short8*)(bb + nt * 1024);
                acc[nt] = __builtin_amdgcn_mfma_f32_16x16x32_bf16(afrag, bfrag, acc[nt], 0, 0, 0);
            }
            __builtin_amdgcn_s_setprio(0);
        }
    }

    // epilogue: D row(M=sample) = q*4+r, col(N) = nt*16+p; add b2, NT store f32
#pragma unroll
    for (int nt = 0; nt < 16; ++nt) {
        int n = nt * 16 + p;
        float b2v = b2[n];
#pragma unroll
        for (int r = 0; r < 4; ++r) {
            int m = m_blk + wave * 16 + q * 4 + r;
            __builtin_nontemporal_store(acc[nt][r] + b2v, out + m * 256 + n);
        }
    }
}

// ---------------------------------------------------------------------------
extern "C" void kernel_launch(void* const* d_in, const int* in_sizes, int n_in,
                              void* d_out, int out_size, void* d_ws, size_t ws_size,
                              hipStream_t stream) {
    const int*   hap    = (const int*)d_in[0];
    const float* tables = (const float*)d_in[1];
    const float* W1     = (const float*)d_in[2];
    const float* b1     = (const float*)d_in[3];
    const float* W2     = (const float*)d_in[4];
    const float* b2     = (const float*)d_in[5];
    float*       outp   = (float*)d_out;

    unsigned short* Tp  = (unsigned short*)d_ws;                        // 4 MB bf16
    unsigned short* W2t = (unsigned short*)d_ws + NLOCI * VOCAB * HID;  // 256 KB
    unsigned short* Hbf = (unsigned short*)d_out;                       // H aliases out

    k_prep<<<dim3(544), dim3(256), 0, stream>>>(tables, W1, b1, W2, Tp, W2t);
    k_gather<<<dim3(NSAMP * 64 / 256), dim3(256), 0, stream>>>(hap, Tp, Hbf);
    k_gemm<<<dim3(NSAMP / 64), dim3(256), 0, stream>>>(Hbf, W2t, b2, outp);
}